// Round 16
// baseline (106.543 us; speedup 1.0000x reference)
//
#include <hip/hip_runtime.h>

#define TPB 256

typedef short bf16x8 __attribute__((ext_vector_type(8)));
typedef float f32x4 __attribute__((ext_vector_type(4)));

__device__ inline unsigned short f2bf(float f) {
    unsigned int u = __float_as_uint(f);
    unsigned int r = (u + 0x7fffu + ((u >> 16) & 1u)) >> 16;
    return (unsigned short)r;
}
__device__ inline float bf2f(unsigned short h) {
    return __uint_as_float(((unsigned int)h) << 16);
}

// async global->LDS 16B copy (dest: linear wave-order, src: per-lane)
__device__ __forceinline__ void gl16(void* lds, const void* g) {
    __builtin_amdgcn_global_load_lds(
        (const __attribute__((address_space(1))) unsigned int*)g,
        (__attribute__((address_space(3))) unsigned int*)lds, 16, 0, 0);
}

// ---------- k1: conv1 tiles (self-contained) + w2r/w3r/zerob/out-init prep + wn2/wn3 ----------
// bid < 1024:  conv1 tile: stage x directly (bf16 + sq ch), w1 raw -> LDS coalesced,
//              reorder LDS->LDS, wn1 in-block, MFMA + fused epilogue.
// bid in [1024, 4343): flat prep: w2r (479232), w3r (368640), zerob (64), out=fc_b (1600)
// bid in [4343, 4487): wn2/wn3 rows (4 per block)
__launch_bounds__(256, 2)
__global__ void conv1_prep(const float* __restrict__ x, const float* __restrict__ w1,
                           const float* __restrict__ w2, const float* __restrict__ w3,
                           const float* __restrict__ stdp, const float* __restrict__ biasp,
                           const float* __restrict__ alphap, const float* __restrict__ fb,
                           unsigned short* __restrict__ w2r, unsigned short* __restrict__ w3r,
                           unsigned short* __restrict__ zerob,
                           float* __restrict__ wn2, float* __restrict__ wn3,
                           float* __restrict__ outp,
                           unsigned short* __restrict__ out,  // h1 [16][64][64][96] bf16 CL
                           float* __restrict__ sqout)         // [16][64][64] fp32
{
    __shared__ unsigned short in_s[22 * 20 * 4];   // 3520 B
    __shared__ unsigned short w_s[96 * 136];       // 26112 B
    __shared__ float w1raw[7200];                  // 28800 B
    __shared__ float s_wn[96];

    int bid = blockIdx.x;
    int tid = threadIdx.x;

    if (bid >= 1024) {
        if (bid < 4343) {
            const int W2N = 479232, E2 = W2N + 368640, E3 = E2 + 64, TOT = E3 + 1600;
            int i = (bid - 1024) * TPB + tid;
            if (i < W2N) {
                int c = i & 31; int r = i >> 5;
                int o = r % 192; r /= 192;
                int tap = r % 26; int cg = r / 26;
                float v = 0.f;
                if (tap < 25) v = w2[((size_t)o * 96 + cg * 32 + c) * 25 + tap];
                w2r[i] = f2bf(v);
            } else if (i < E2) {
                int idx = i - W2N;
                int c = idx & 31; int r = idx >> 5;
                int o = r % 192; r /= 192;
                int tap = r % 10; int cg = r / 10;
                float v = 0.f;
                if (tap < 9) v = w3[((size_t)o * 192 + cg * 32 + c) * 9 + tap];
                w3r[idx] = f2bf(v);
            } else if (i < E3) {
                zerob[i - E2] = 0;
            } else if (i < TOT) {
                int t = i - E3;
                outp[t] = fb[t % 100];
            }
        } else {
            int o = (bid - 4343) * 4 + (tid >> 6);  // 0..575
            int lane = tid & 63;
            const float* row; float* dst; int D;
            if (o < 192) { row = w2 + (size_t)o * 2400;        D = 2400; dst = wn2 + o; }
            else         { int r = o - 192; row = w3 + (size_t)r * 1728; D = 1728; dst = wn3 + r; }
            float acc = 0.f;
            for (int i = lane; i < D; i += 64) { float v = row[i]; acc += v * v; }
            #pragma unroll
            for (int off = 32; off >= 1; off >>= 1) acc += __shfl_down(acc, off);
            if (lane == 0) *dst = acc;
        }
        return;
    }

    // ---- conv1 tile ----
    int tx = bid & 7; bid >>= 3;
    int ty = bid & 7; bid >>= 3;
    int b = bid;
    int x0 = tx * 16, y0 = ty * 16;
    int lane = tid & 63, wv = tid >> 6;
    int col = lane & 15, kg = lane >> 4;

    // coalesced: raw w1 -> LDS
    for (int idx = tid; idx < 7200; idx += 256) w1raw[idx] = w1[idx];
    // stage x tile directly (bf16 + sq channel; identical rounding to xbf path)
    for (int idx = tid; idx < 21 * 20; idx += 256) {
        int py = idx / 20, px = idx - py * 20;
        int gy = y0 - 2 + py, gx = x0 - 2 + px;
        ushort4 v = make_ushort4(0, 0, 0, 0);
        if (gy >= 0 && gy < 128 && gx >= 0 && gx < 128) {
            const float* xb = x + (size_t)b * 49152 + gy * 128 + gx;
            float v0 = xb[0], v1 = xb[16384], v2 = xb[32768];
            v = make_ushort4(f2bf(v0), f2bf(v1), f2bf(v2),
                             f2bf(v0 * v0 + v1 * v1 + v2 * v2));
        }
        *(ushort4*)&in_s[idx * 4] = v;
    }
    __syncthreads();   // w1raw ready

    // reorder w1 (LDS->LDS): [96][136], d = tp*4+c, tp = ki*6+kj; c3 = -0.5 on real taps
    for (int idx = tid; idx < 13056; idx += 256) {
        int o = idx / 136, d = idx - o * 136;
        int tp = d >> 2, c = d & 3;
        float v = 0.f;
        if (tp < 30) {
            int ki = tp / 6, kj = tp - 6 * ki;
            if (kj < 5) v = (c < 3) ? w1raw[o * 75 + c * 25 + ki * 5 + kj] : -0.5f;
        }
        w_s[idx] = f2bf(v);
    }
    // wn1 in-block (reads LDS): 2 threads per o-row
    if (tid < 192) {
        int row = tid >> 1, half = tid & 1;
        int i0 = half ? 38 : 0, i1 = half ? 75 : 38;
        float a = 0.f;
        for (int i = i0; i < i1; ++i) { float v = w1raw[row * 75 + i]; a += v * v; }
        a += __shfl_xor(a, 1);
        if (half == 0) s_wn[row] = a;
    }
    __syncthreads();

    f32x4 acc[6][4];
    #pragma unroll
    for (int mt = 0; mt < 6; ++mt)
        #pragma unroll
        for (int n = 0; n < 4; ++n) acc[mt][n] = (f32x4){0.f, 0.f, 0.f, 0.f};

    #pragma unroll
    for (int ks = 0; ks < 4; ++ks) {
        int tap0 = ks * 8 + kg * 2;
        int ki = tap0 / 6, kj = tap0 - 6 * ki;
        bf16x8 bfrag[4];
        #pragma unroll
        for (int n = 0; n < 4; ++n) {
            int row = wv * 4 + n + ki;
            int ix = col + kj;
            const unsigned short* p = &in_s[(row * 20 + ix) * 4];
            union { bf16x8 v; uint2 u[2]; } tmp;
            tmp.u[0] = *(const uint2*)p;
            tmp.u[1] = *(const uint2*)(p + 4);
            bfrag[n] = tmp.v;
        }
        bf16x8 afrag[6];
        #pragma unroll
        for (int mt = 0; mt < 6; ++mt)
            afrag[mt] = *(const bf16x8*)&w_s[(mt * 16 + col) * 136 + ks * 32 + kg * 8];
        #pragma unroll
        for (int mt = 0; mt < 6; ++mt)
            #pragma unroll
            for (int n = 0; n < 4; ++n)
                acc[mt][n] = __builtin_amdgcn_mfma_f32_16x16x32_bf16(
                    afrag[mt], bfrag[n], acc[mt][n], 0, 0, 0);
    }

    // acc = cross - 0.5*pn  ->  d2 = wn - 2*acc
    float stdv = stdp[0], biasv = biasp[0];
    float inv2s2 = 1.f / (2.f * stdv * stdv);
    float a00 = alphap[0], a01 = alphap[1], a10 = alphap[2], a11 = alphap[3];
    int dx = col & 1;
    float ax0 = dx ? a01 : a00;
    float ax1 = dx ? a11 : a10;

    float sqa[2] = {0.f, 0.f};
    #pragma unroll
    for (int mt = 0; mt < 6; ++mt) {
        #pragma unroll
        for (int p2 = 0; p2 < 2; ++p2) {
            unsigned short res[4];
            #pragma unroll
            for (int r = 0; r < 4; ++r) {
                int o = mt * 16 + kg * 4 + r;
                float wno = s_wn[o];
                float d20 = fmaxf(wno - 2.f * acc[mt][2 * p2][r], 0.f);
                float d21 = fmaxf(wno - 2.f * acc[mt][2 * p2 + 1][r], 0.f);
                float g0 = __expf(-d20 * inv2s2);
                float g1 = __expf(-d21 * inv2s2);
                g0 = (g0 >= biasv) ? g0 : 0.f;
                g1 = (g1 >= biasv) ? g1 : 0.f;
                float s = ax0 * g0 + ax1 * g1;
                s += __shfl_xor(s, 1);
                res[r] = f2bf(0.25f * s);
                float vv = bf2f(res[r]);
                sqa[p2] += vv * vv;
            }
            if (dx == 0) {
                int yo = ty * 8 + wv * 2 + p2, xo = tx * 8 + (col >> 1);
                *(ushort4*)&out[(((size_t)b * 64 + yo) * 64 + xo) * 96 + mt * 16 + kg * 4] =
                    make_ushort4(res[0], res[1], res[2], res[3]);
            }
        }
    }
    #pragma unroll
    for (int p2 = 0; p2 < 2; ++p2) {
        float s = sqa[p2];
        s += __shfl_xor(s, 16);
        s += __shfl_xor(s, 32);
        if (dx == 0 && kg == 0) {
            int yo = ty * 8 + wv * 2 + p2, xo = tx * 8 + (col >> 1);
            sqout[((size_t)b * 64 + yo) * 64 + xo] = s;
        }
    }
}

// ---------- conv2: 192o x 128px per block, 4 waves (2m x 2n), zero-skip before weights ----------
__launch_bounds__(256, 2)
__global__ void conv2_mfma(const unsigned short* __restrict__ hin,
                           const unsigned short* __restrict__ wt2,  // [3][26][192][32]
                           const float* __restrict__ sq1,           // [16][64][64] fp32
                           const float* __restrict__ wn,
                           const float* __restrict__ stdp, const float* __restrict__ biasp,
                           const float* __restrict__ alphap,
                           const unsigned short* __restrict__ zerob,
                           unsigned short* __restrict__ hout) // [16][32][32][192] CL bf16
{
    __shared__ unsigned short in_s[240 * 32];       // 15360 B
    __shared__ unsigned short w_s[2][2 * 192 * 32]; // 49152 B
    __shared__ float sq_s[240];
    __shared__ int s_nz[4];

    int bid = blockIdx.x;
    int xt = bid & 3; bid >>= 2;
    int yt = bid & 7; bid >>= 3;
    int b = bid;
    int x0 = xt * 16, y0 = yt * 8;
    int tid = threadIdx.x;
    int lane = tid & 63, wid = tid >> 6;
    int wave_m = wid >> 1, wave_n = wid & 1;
    int col = lane & 15, kg = lane >> 4;
    int coly = col >> 3, colx = col & 7;

    if (tid < 240) {
        int r = tid / 20, c = tid - r * 20;
        int gy = y0 - 2 + r, gx = x0 - 2 + c;
        float v = 0.f;
        if (gy >= 0 && gy < 64 && gx >= 0 && gx < 64)
            v = sq1[((size_t)b * 64 + gy) * 64 + gx];
        sq_s[tid] = v;
    }

    f32x4 acc[6][4];
    #pragma unroll
    for (int mt = 0; mt < 6; ++mt)
        #pragma unroll
        for (int nt = 0; nt < 4; ++nt) acc[mt][nt] = (f32x4){0.f, 0.f, 0.f, 0.f};

    for (int cg = 0; cg < 3; ++cg) {
        #pragma unroll
        for (int i = 0; i < 4; ++i) {
            int chunk = tid + i * 256;
            if (chunk < 960) {
                int px = chunk >> 2, c16 = chunk & 3;
                int iy = px / 20, ix = px - iy * 20;
                int gy = y0 - 2 + iy, gx = x0 - 2 + ix;
                const void* src = (gy >= 0 && gy < 64 && gx >= 0 && gx < 64)
                    ? (const void*)&hin[(((size_t)b * 64 + gy) * 64 + gx) * 96 + cg * 32 + c16 * 8]
                    : (const void*)zerob;
                gl16(&in_s[chunk * 8], src);
            }
        }
        __syncthreads();   // in_s ready

        unsigned int nzb = 0;
        #pragma unroll
        for (int i = 0; i < 4; ++i) {
            int chunk = tid + i * 256;
            if (chunk < 960) {
                uint4 v = *(const uint4*)&in_s[chunk * 8];
                nzb |= v.x | v.y | v.z | v.w;
            }
        }
        bool any = __any(nzb != 0);
        if (lane == 0) s_nz[wid] = any ? 1 : 0;
        __syncthreads();
        if (s_nz[0] | s_nz[1] | s_nz[2] | s_nz[3]) {
            #pragma unroll
            for (int i = 0; i < 6; ++i) {
                int chunk = tid + i * 256;
                int tp = chunk / 768, rem = chunk - tp * 768;
                gl16(&w_s[0][tp * 6144 + rem * 8],
                     &wt2[(((size_t)cg * 26 + tp) * 192) * 32 + rem * 8]);
            }
            __syncthreads();
            for (int pr = 0; pr < 13; ++pr) {
                int cur = pr & 1;
                if (pr < 12) {
                    #pragma unroll
                    for (int i = 0; i < 6; ++i) {
                        int chunk = tid + i * 256;
                        int tp = chunk / 768, rem = chunk - tp * 768;
                        gl16(&w_s[cur ^ 1][tp * 6144 + rem * 8],
                             &wt2[(((size_t)cg * 26 + (pr + 1) * 2 + tp) * 192) * 32 + rem * 8]);
                    }
                }
                #pragma unroll
                for (int t2 = 0; t2 < 2; ++t2) {
                    int tap = pr * 2 + t2;
                    int ki = tap / 5, kj = tap - 5 * ki;
                    if (tap >= 25) { ki = 0; kj = 0; }
                    bf16x8 bfrag[4], afrag[6];
                    #pragma unroll
                    for (int nt = 0; nt < 4; ++nt) {
                        int yy = 2 * nt + coly + ki;
                        int xx = wave_n * 8 + colx + kj;
                        bfrag[nt] = *(const bf16x8*)&in_s[(yy * 20 + xx) * 32 + kg * 8];
                    }
                    #pragma unroll
                    for (int mt = 0; mt < 6; ++mt)
                        afrag[mt] = *(const bf16x8*)
                            &w_s[cur][t2 * 6144 + (wave_m * 96 + mt * 16 + col) * 32 + kg * 8];
                    #pragma unroll
                    for (int mt = 0; mt < 6; ++mt)
                        #pragma unroll
                        for (int nt = 0; nt < 4; ++nt)
                            acc[mt][nt] = __builtin_amdgcn_mfma_f32_16x16x32_bf16(
                                afrag[mt], bfrag[nt], acc[mt][nt], 0, 0, 0);
                }
                __syncthreads();
            }
        }
    }

    float stdv = stdp[0], biasv = biasp[0];
    float inv2s2 = 1.f / (2.f * stdv * stdv);
    float a_own = alphap[coly * 2 + (col & 1)];
    #pragma unroll
    for (int nt = 0; nt < 4; ++nt) {
        int ly = 2 * nt + coly + 2;
        int lx = wave_n * 8 + colx + 2;
        float pnv = 0.f;
        #pragma unroll
        for (int dy = -2; dy <= 2; ++dy)
            #pragma unroll
            for (int dx2 = -2; dx2 <= 2; ++dx2)
                pnv += sq_s[(ly + dy) * 20 + (lx + dx2)];
        int x = x0 + wave_n * 8 + colx;
        int yo = (y0 >> 1) + nt;
        int xo = x >> 1;
        #pragma unroll
        for (int mt = 0; mt < 6; ++mt) {
            int ob = wave_m * 96 + mt * 16 + (kg << 2);
            unsigned short res[4];
            #pragma unroll
            for (int r = 0; r < 4; ++r) {
                float d2 = fmaxf(pnv + wn[ob + r] - 2.f * acc[mt][nt][r], 0.f);
                float g = __expf(-d2 * inv2s2);
                g = (g >= biasv) ? g : 0.f;
                g *= a_own;
                g += __shfl_xor(g, 1);
                g += __shfl_xor(g, 8);
                res[r] = f2bf(0.25f * g);
            }
            if (((col & 1) == 0) && ((col & 8) == 0)) {
                *(ushort4*)&hout[(((size_t)b * 32 + yo) * 32 + xo) * 192 + ob] =
                    make_ushort4(res[0], res[1], res[2], res[3]);
            }
        }
    }
}

// ---------- conv3: MFMA bf16, grid 512, 4 waves x (48o x 64px), 16x8 tile, inline pn3 ----------
__launch_bounds__(256, 2)
__global__ void conv3_mfma(const unsigned short* __restrict__ hin,  // [16][32][32][192] CL
                           const unsigned short* __restrict__ wt3,  // [6][10][192][32]
                           const float* __restrict__ wn,
                           const float* __restrict__ stdp, const float* __restrict__ biasp,
                           const unsigned short* __restrict__ zerob,
                           unsigned short* __restrict__ hout) // [16][384*1024] bf16 CF
{
    __shared__ unsigned short in_s[180 * 32];      // [10][18][32c] 11520 B
    __shared__ unsigned short w_s[2][2 * 96 * 32]; // 24576 B
    __shared__ float pnacc[180];

    int bid = blockIdx.x;
    int sp = bid & 7; bid >>= 3;
    int ot = bid & 3; int b = bid >> 2;
    int x0 = (sp & 1) * 16, y0 = (sp >> 1) * 8, o0 = ot * 96;
    int tid = threadIdx.x;
    int lane = tid & 63, wid = tid >> 6;
    int om = wid >> 1, wn2 = wid & 1;
    int col = lane & 15, kg = lane >> 4;
    int coly = col >> 3, colx = col & 7;

    if (tid < 180) pnacc[tid] = 0.f;

    f32x4 acc[3][4];
    #pragma unroll
    for (int mt = 0; mt < 3; ++mt)
        #pragma unroll
        for (int nt = 0; nt < 4; ++nt) acc[mt][nt] = (f32x4){0.f, 0.f, 0.f, 0.f};

    for (int cg = 0; cg < 6; ++cg) {
        #pragma unroll
        for (int i = 0; i < 3; ++i) {
            int chunk = tid + i * 256;
            if (chunk < 720) {
                int px = chunk >> 2, c16 = chunk & 3;
                int iy = px / 18, ix = px - iy * 18;
                int gy = y0 - 1 + iy, gx = x0 - 1 + ix;
                const void* src = (gy >= 0 && gy < 32 && gx >= 0 && gx < 32)
                    ? (const void*)&hin[(((size_t)b * 32 + gy) * 32 + gx) * 192 + cg * 32 + c16 * 8]
                    : (const void*)zerob;
                gl16(&in_s[chunk * 8], src);
            }
        }
        #pragma unroll
        for (int i = 0; i < 3; ++i) {
            int chunk = tid + i * 256;
            int tp = chunk / 384, rem = chunk - tp * 384;
            gl16(&w_s[0][tp * 3072 + rem * 8],
                 &wt3[(((size_t)cg * 10 + tp) * 192 + o0) * 32 + rem * 8]);
        }
        __syncthreads();

        if (tid < 180) {
            const unsigned short* p = &in_s[tid * 32];
            float a = 0.f;
            #pragma unroll
            for (int c = 0; c < 32; c += 8) {
                bf16x8 v = *(const bf16x8*)&p[c];
                #pragma unroll
                for (int j = 0; j < 8; ++j) { float f = bf2f((unsigned short)v[j]); a += f * f; }
            }
            pnacc[tid] += a;
        }

        for (int pr = 0; pr < 5; ++pr) {
            int cur = pr & 1;
            if (pr < 4) {
                #pragma unroll
                for (int i = 0; i < 3; ++i) {
                    int chunk = tid + i * 256;
                    int tp = chunk / 384, rem = chunk - tp * 384;
                    gl16(&w_s[cur ^ 1][tp * 3072 + rem * 8],
                         &wt3[(((size_t)cg * 10 + (pr + 1) * 2 + tp) * 192 + o0) * 32 + rem * 8]);
                }
            }
            #pragma unroll
            for (int t2 = 0; t2 < 2; ++t2) {
                int tap = pr * 2 + t2;
                int ki = tap / 3, kj = tap - 3 * ki;
                if (tap >= 9) { ki = 0; kj = 0; }
                bf16x8 bfrag[4], afrag[3];
                #pragma unroll
                for (int nt = 0; nt < 4; ++nt) {
                    int yy = 2 * nt + coly + ki;
                    int xx = wn2 * 8 + colx + kj;
                    bfrag[nt] = *(const bf16x8*)&in_s[(yy * 18 + xx) * 32 + kg * 8];
                }
                #pragma unroll
                for (int mt = 0; mt < 3; ++mt)
                    afrag[mt] = *(const bf16x8*)
                        &w_s[cur][(t2 * 96 + om * 48 + mt * 16 + col) * 32 + kg * 8];
                #pragma unroll
                for (int mt = 0; mt < 3; ++mt)
                    #pragma unroll
                    for (int nt = 0; nt < 4; ++nt)
                        acc[mt][nt] = __builtin_amdgcn_mfma_f32_16x16x32_bf16(
                            afrag[mt], bfrag[nt], acc[mt][nt], 0, 0, 0);
            }
            __syncthreads();
        }
    }

    float stdv = stdp[0], biasv = biasp[0];
    float inv2s2 = 1.f / (2.f * stdv * stdv);
    #pragma unroll
    for (int nt = 0; nt < 4; ++nt) {
        int y = y0 + 2 * nt + coly;
        int x = x0 + wn2 * 8 + colx;
        int ly = 2 * nt + coly + 1, lx = wn2 * 8 + colx + 1;
        float pnv = 0.f;
        #pragma unroll
        for (int dy = -1; dy <= 1; ++dy)
            #pragma unroll
            for (int dx = -1; dx <= 1; ++dx)
                pnv += pnacc[(ly + dy) * 18 + (lx + dx)];
        #pragma unroll
        for (int mt = 0; mt < 3; ++mt) {
            int ob = o0 + om * 48 + mt * 16 + (kg << 2);
            #pragma unroll
            for (int r = 0; r < 4; ++r) {
                float d2 = fmaxf(pnv + wn[ob + r] - 2.f * acc[mt][nt][r], 0.f);
                float g = __expf(-d2 * inv2s2);
                g = (g >= biasv) ? g : 0.f;
                hout[((size_t)b * 384 + ob + r) * 1024 + y * 32 + x] = f2bf(g);
            }
        }
    }
}

// ---------- FC: MFMA over K-chunks, zero-chunk skip, atomic accumulate into out ----------
// out pre-initialized to fb by k1. Zero chunks contribute nothing (no atomics fire).
__launch_bounds__(256, 4)
__global__ void fc_mfma(const unsigned short* __restrict__ h3bf,
                        const float* __restrict__ fw,
                        float* __restrict__ outp)  // [16][100]
{
    __shared__ unsigned short h3s[16 * 520];
    __shared__ unsigned short fws[16 * 520];
    __shared__ float red[4][16][16];
    __shared__ int s_nz[4];
    const size_t KI = 393216;
    int ch = blockIdx.x;
    int i0 = ch * 512;
    int tid = threadIdx.x;
    int lane = tid & 63, wv = tid >> 6;
    int col = lane & 15, kg = lane >> 4;

    unsigned int nzbits = 0;
    #pragma unroll
    for (int it = 0; it < 4; ++it) {
        int c = tid + it * 256;
        int b = c >> 6, off = (c & 63) * 8;
        bf16x8 v = *(const bf16x8*)&h3bf[(size_t)b * KI + i0 + off];
        union { bf16x8 s; unsigned int u[4]; } cv; cv.s = v;
        nzbits |= cv.u[0] | cv.u[1] | cv.u[2] | cv.u[3];
        *(bf16x8*)&h3s[b * 520 + off] = v;
    }
    bool any = __any(nzbits != 0);
    if (lane == 0) s_nz[wv] = any ? 1 : 0;
    __syncthreads();
    if (!(s_nz[0] | s_nz[1] | s_nz[2] | s_nz[3])) return;  // exact: zero contribution

    float4 pre[8];
    #pragma unroll
    for (int it = 0; it < 8; ++it) {
        int c = tid + it * 256;
        int row = c >> 7, off4 = (c & 127) * 4;
        pre[it] = (row < 100) ? *(const float4*)&fw[(size_t)row * KI + i0 + off4]
                              : make_float4(0.f, 0.f, 0.f, 0.f);
    }

    for (int jt = 0; jt < 7; ++jt) {
        int j0 = jt * 16;
        #pragma unroll
        for (int it = 0; it < 8; ++it) {
            int c = tid + it * 256;
            int row = c >> 7, off4 = (c & 127) * 4;
            *(ushort4*)&fws[row * 520 + off4] =
                make_ushort4(f2bf(pre[it].x), f2bf(pre[it].y), f2bf(pre[it].z), f2bf(pre[it].w));
        }
        if (jt < 6) {
            #pragma unroll
            for (int it = 0; it < 8; ++it) {
                int c = tid + it * 256;
                int row = c >> 7, off4 = (c & 127) * 4;
                int j = j0 + 16 + row;
                pre[it] = (j < 100) ? *(const float4*)&fw[(size_t)j * KI + i0 + off4]
                                    : make_float4(0.f, 0.f, 0.f, 0.f);
            }
        }
        __syncthreads();
        f32x4 acc = (f32x4){0.f, 0.f, 0.f, 0.f};
        #pragma unroll
        for (int s = 0; s < 4; ++s) {
            int k = wv * 128 + s * 32 + kg * 8;
            bf16x8 af = *(const bf16x8*)&fws[col * 520 + k];
            bf16x8 bg = *(const bf16x8*)&h3s[col * 520 + k];
            acc = __builtin_amdgcn_mfma_f32_16x16x32_bf16(af, bg, acc, 0, 0, 0);
        }
        #pragma unroll
        for (int r = 0; r < 4; ++r) red[wv][kg * 4 + r][col] = acc[r];
        __syncthreads();
        int j = tid >> 4, bb = tid & 15;
        float s = red[0][j][bb] + red[1][j][bb] + red[2][j][bb] + red[3][j][bb];
        if (j0 + j < 100)
            atomicAdd(&outp[bb * 100 + j0 + j], s);
        __syncthreads();
    }
}

// ---------- launch ----------
extern "C" void kernel_launch(void* const* d_in, const int* in_sizes, int n_in,
                              void* d_out, int out_size, void* d_ws, size_t ws_size,
                              hipStream_t stream) {
    const float* x      = (const float*)d_in[0];
    const float* w1     = (const float*)d_in[1];
    const float* std1   = (const float*)d_in[2];
    const float* bias1  = (const float*)d_in[3];
    const float* alpha1 = (const float*)d_in[4];
    const float* w2     = (const float*)d_in[5];
    const float* std2   = (const float*)d_in[6];
    const float* bias2  = (const float*)d_in[7];
    const float* alpha2 = (const float*)d_in[8];
    const float* w3     = (const float*)d_in[9];
    const float* std3   = (const float*)d_in[10];
    const float* bias3  = (const float*)d_in[11];
    const float* fc_w   = (const float*)d_in[12];
    const float* fc_b   = (const float*)d_in[13];
    float* out = (float*)d_out;
    float* ws  = (float*)d_ws;

    // float region
    float* sbuf  = ws;                  // 65536 (sq1 plane 16*64*64)
    float* wn2   = sbuf + 65536;        // 192
    float* wn3   = wn2 + 192;           // 384
    float* rest  = wn3 + 384 + 32;      // pad -> 16B aligned
    // ushort region
    unsigned short* h1bf = (unsigned short*)rest;  // 6291456
    unsigned short* h2bf = h1bf + 6291456;         // 3145728
    unsigned short* h3bf = h2bf + 3145728;         // 6291456
    unsigned short* w2r  = h3bf + 6291456;         // 479232
    unsigned short* w3r  = w2r + 479232;           // 368640
    unsigned short* zerob = w3r + 368640;          // 64

    dim3 B(TPB);

    // k1: conv1 tiles + all remaining prep (incl. out = fc_b init)
    conv1_prep<<<dim3(4487), B, 0, stream>>>(
        x, w1, w2, w3, std1, bias1, alpha1, fc_b,
        w2r, w3r, zerob, wn2, wn3, out, h1bf, sbuf);

    conv2_mfma<<<dim3(512), B, 0, stream>>>(
        h1bf, w2r, sbuf, wn2, std2, bias2, alpha2, zerob, h2bf);

    conv3_mfma<<<dim3(512), B, 0, stream>>>(
        h2bf, w3r, wn3, std3, bias3, zerob, h3bf);

    fc_mfma<<<dim3(768), B, 0, stream>>>(h3bf, fc_w, out);
}

// Round 17
// 94.307 us; speedup vs baseline: 1.1298x; 1.1298x over previous
//
#include <hip/hip_runtime.h>

#define TPB 256

typedef short bf16x8 __attribute__((ext_vector_type(8)));
typedef float f32x4 __attribute__((ext_vector_type(4)));

__device__ inline unsigned short f2bf(float f) {
    unsigned int u = __float_as_uint(f);
    unsigned int r = (u + 0x7fffu + ((u >> 16) & 1u)) >> 16;
    return (unsigned short)r;
}
__device__ inline float bf2f(unsigned short h) {
    return __uint_as_float(((unsigned int)h) << 16);
}

// async global->LDS 16B copy (dest: linear wave-order, src: per-lane)
__device__ __forceinline__ void gl16(void* lds, const void* g) {
    __builtin_amdgcn_global_load_lds(
        (const __attribute__((address_space(1))) unsigned int*)g,
        (__attribute__((address_space(3))) unsigned int*)lds, 16, 0, 0);
}

// ---------- fused prep: xbf (+sq), weight reorders, out=fc_b init, weight norms ----------
__global__ void prep_all(const float* __restrict__ x,
                         const float* __restrict__ w1, const float* __restrict__ w2,
                         const float* __restrict__ w3, const float* __restrict__ fb,
                         unsigned short* __restrict__ xbf,
                         unsigned short* __restrict__ w1r, unsigned short* __restrict__ w2r,
                         unsigned short* __restrict__ w3r, unsigned short* __restrict__ zerob,
                         float* __restrict__ outp,
                         float* __restrict__ wn1, float* __restrict__ wn2,
                         float* __restrict__ wn3) {
    int bid = blockIdx.x;
    int tid = threadIdx.x;
    if (bid < 1024) {
        int idx = bid * TPB + tid;
        int b = idx >> 14, px = idx & 16383;
        const float* xb = x + (size_t)b * 3 * 16384 + px;
        float v0 = xb[0], v1 = xb[16384], v2 = xb[32768];
        ushort4 v;
        v.x = f2bf(v0); v.y = f2bf(v1); v.z = f2bf(v2);
        v.w = f2bf(v0 * v0 + v1 * v1 + v2 * v2);
        *(ushort4*)&xbf[(size_t)idx * 4] = v;
    } else if (bid < 4394) {
        int idx = (bid - 1024) * TPB + tid;
        if (idx < 13056) {
            int o = idx / 136, d = idx - o * 136;
            int tp = d >> 2, c = d & 3;
            float v = 0.f;
            if (tp < 30) {
                int ki = tp / 6, kj = tp - 6 * ki;
                if (kj < 5) v = (c < 3) ? w1[o * 75 + c * 25 + ki * 5 + kj] : -0.5f;
            }
            w1r[idx] = f2bf(v);
        } else if (idx < 492288) {
            int i = idx - 13056;
            int c = i & 31; int r = i >> 5;
            int o = r % 192; r /= 192;
            int tap = r % 26; int cg = r / 26;
            float v = 0.f;
            if (tap < 25) v = w2[((size_t)o * 96 + cg * 32 + c) * 25 + tap];
            w2r[i] = f2bf(v);
        } else if (idx < 860928) {
            int i = idx - 492288;
            int c = i & 31; int r = i >> 5;
            int o = r % 192; r /= 192;
            int tap = r % 10; int cg = r / 10;
            float v = 0.f;
            if (tap < 9) v = w3[((size_t)o * 192 + cg * 32 + c) * 9 + tap];
            w3r[i] = f2bf(v);
        } else if (idx < 860992) {
            zerob[idx - 860928] = 0;
        } else if (idx < 862592) {
            int t = idx - 860992;
            outp[t] = fb[t % 100];
        }
    } else {
        int o = (bid - 4394) * 4 + (tid >> 6);
        int lane = tid & 63;
        const float* row; float* dst; int D;
        if (o < 96)       { row = w1 + (size_t)o * 75;           D = 75;   dst = wn1 + o; }
        else if (o < 288) { int r = o - 96;  row = w2 + (size_t)r * 2400; D = 2400; dst = wn2 + r; }
        else              { int r = o - 288; row = w3 + (size_t)r * 1728; D = 1728; dst = wn3 + r; }
        float acc = 0.f;
        for (int i = lane; i < D; i += 64) { float v = row[i]; acc += v * v; }
        #pragma unroll
        for (int off = 32; off >= 1; off >>= 1) acc += __shfl_down(acc, off);
        if (lane == 0) *dst = acc;
    }
}

// ---------- conv1: MFMA bf16, K=128 (32 taps x 4c, c3 = -0.5*sq -> pn folded in) ----------
__launch_bounds__(256, 2)
__global__ void conv1_mfma(const unsigned short* __restrict__ xbf,
                           const unsigned short* __restrict__ w1r,
                           const float* __restrict__ wn,
                           const float* __restrict__ stdp, const float* __restrict__ biasp,
                           const float* __restrict__ alphap,
                           unsigned short* __restrict__ out,  // [16][64][64][96] bf16 CL
                           float* __restrict__ sqout)         // [16][64][64] fp32
{
    __shared__ unsigned short in_s[22 * 20 * 4];
    __shared__ unsigned short w_s[96 * 136];

    int bid = blockIdx.x;
    int tx = bid & 7; bid >>= 3;
    int ty = bid & 7; bid >>= 3;
    int b = bid;
    int x0 = tx * 16, y0 = ty * 16;
    int tid = threadIdx.x;
    int lane = tid & 63, wv = tid >> 6;
    int col = lane & 15, kg = lane >> 4;

    for (int idx = tid; idx < 21 * 20; idx += 256) {
        int py = idx / 20, px = idx - py * 20;
        int gy = y0 - 2 + py, gx = x0 - 2 + px;
        ushort4 v = make_ushort4(0, 0, 0, 0);
        if (gy >= 0 && gy < 128 && gx >= 0 && gx < 128)
            v = *(const ushort4*)&xbf[(((size_t)b * 128 + gy) * 128 + gx) * 4];
        *(ushort4*)&in_s[idx * 4] = v;
    }
    for (int idx = tid; idx < 1632; idx += 256)
        *(bf16x8*)&w_s[idx * 8] = *(const bf16x8*)&w1r[idx * 8];
    __syncthreads();

    f32x4 acc[6][4];
    #pragma unroll
    for (int mt = 0; mt < 6; ++mt)
        #pragma unroll
        for (int n = 0; n < 4; ++n) acc[mt][n] = (f32x4){0.f, 0.f, 0.f, 0.f};

    #pragma unroll
    for (int ks = 0; ks < 4; ++ks) {
        int tap0 = ks * 8 + kg * 2;
        int ki = tap0 / 6, kj = tap0 - 6 * ki;
        bf16x8 bfrag[4];
        #pragma unroll
        for (int n = 0; n < 4; ++n) {
            int row = wv * 4 + n + ki;
            int ix = col + kj;
            const unsigned short* p = &in_s[(row * 20 + ix) * 4];
            union { bf16x8 v; uint2 u[2]; } tmp;
            tmp.u[0] = *(const uint2*)p;
            tmp.u[1] = *(const uint2*)(p + 4);
            bfrag[n] = tmp.v;
        }
        bf16x8 afrag[6];
        #pragma unroll
        for (int mt = 0; mt < 6; ++mt)
            afrag[mt] = *(const bf16x8*)&w_s[(mt * 16 + col) * 136 + ks * 32 + kg * 8];
        #pragma unroll
        for (int mt = 0; mt < 6; ++mt)
            #pragma unroll
            for (int n = 0; n < 4; ++n)
                acc[mt][n] = __builtin_amdgcn_mfma_f32_16x16x32_bf16(
                    afrag[mt], bfrag[n], acc[mt][n], 0, 0, 0);
    }

    float stdv = stdp[0], biasv = biasp[0];
    float inv2s2 = 1.f / (2.f * stdv * stdv);
    float a00 = alphap[0], a01 = alphap[1], a10 = alphap[2], a11 = alphap[3];
    int dx = col & 1;
    float ax0 = dx ? a01 : a00;
    float ax1 = dx ? a11 : a10;

    float sqa[2] = {0.f, 0.f};
    #pragma unroll
    for (int mt = 0; mt < 6; ++mt) {
        #pragma unroll
        for (int p2 = 0; p2 < 2; ++p2) {
            unsigned short res[4];
            #pragma unroll
            for (int r = 0; r < 4; ++r) {
                int o = mt * 16 + kg * 4 + r;
                float wno = wn[o];
                float d20 = fmaxf(wno - 2.f * acc[mt][2 * p2][r], 0.f);
                float d21 = fmaxf(wno - 2.f * acc[mt][2 * p2 + 1][r], 0.f);
                float g0 = __expf(-d20 * inv2s2);
                float g1 = __expf(-d21 * inv2s2);
                g0 = (g0 >= biasv) ? g0 : 0.f;
                g1 = (g1 >= biasv) ? g1 : 0.f;
                float s = ax0 * g0 + ax1 * g1;
                s += __shfl_xor(s, 1);
                res[r] = f2bf(0.25f * s);
                float vv = bf2f(res[r]);
                sqa[p2] += vv * vv;
            }
            if (dx == 0) {
                int yo = ty * 8 + wv * 2 + p2, xo = tx * 8 + (col >> 1);
                *(ushort4*)&out[(((size_t)b * 64 + yo) * 64 + xo) * 96 + mt * 16 + kg * 4] =
                    make_ushort4(res[0], res[1], res[2], res[3]);
            }
        }
    }
    #pragma unroll
    for (int p2 = 0; p2 < 2; ++p2) {
        float s = sqa[p2];
        s += __shfl_xor(s, 16);
        s += __shfl_xor(s, 32);
        if (dx == 0 && kg == 0) {
            int yo = ty * 8 + wv * 2 + p2, xo = tx * 8 + (col >> 1);
            sqout[((size_t)b * 64 + yo) * 64 + xo] = s;
        }
    }
}

// ---------- conv2: 192o x 128px per block, 4 waves (2m x 2n), zero-skip before weights ----------
__launch_bounds__(256, 2)
__global__ void conv2_mfma(const unsigned short* __restrict__ hin,
                           const unsigned short* __restrict__ wt2,  // [3][26][192][32]
                           const float* __restrict__ sq1,           // [16][64][64] fp32
                           const float* __restrict__ wn,
                           const float* __restrict__ stdp, const float* __restrict__ biasp,
                           const float* __restrict__ alphap,
                           const unsigned short* __restrict__ zerob,
                           unsigned short* __restrict__ hout) // [16][32][32][192] CL bf16
{
    __shared__ unsigned short in_s[240 * 32];       // 15360 B
    __shared__ unsigned short w_s[2][2 * 192 * 32]; // 49152 B
    __shared__ float sq_s[240];
    __shared__ int s_nz[4];

    int bid = blockIdx.x;
    int xt = bid & 3; bid >>= 2;
    int yt = bid & 7; bid >>= 3;
    int b = bid;
    int x0 = xt * 16, y0 = yt * 8;
    int tid = threadIdx.x;
    int lane = tid & 63, wid = tid >> 6;
    int wave_m = wid >> 1, wave_n = wid & 1;
    int col = lane & 15, kg = lane >> 4;
    int coly = col >> 3, colx = col & 7;

    if (tid < 240) {
        int r = tid / 20, c = tid - r * 20;
        int gy = y0 - 2 + r, gx = x0 - 2 + c;
        float v = 0.f;
        if (gy >= 0 && gy < 64 && gx >= 0 && gx < 64)
            v = sq1[((size_t)b * 64 + gy) * 64 + gx];
        sq_s[tid] = v;
    }

    f32x4 acc[6][4];
    #pragma unroll
    for (int mt = 0; mt < 6; ++mt)
        #pragma unroll
        for (int nt = 0; nt < 4; ++nt) acc[mt][nt] = (f32x4){0.f, 0.f, 0.f, 0.f};

    for (int cg = 0; cg < 3; ++cg) {
        #pragma unroll
        for (int i = 0; i < 4; ++i) {
            int chunk = tid + i * 256;
            if (chunk < 960) {
                int px = chunk >> 2, c16 = chunk & 3;
                int iy = px / 20, ix = px - iy * 20;
                int gy = y0 - 2 + iy, gx = x0 - 2 + ix;
                const void* src = (gy >= 0 && gy < 64 && gx >= 0 && gx < 64)
                    ? (const void*)&hin[(((size_t)b * 64 + gy) * 64 + gx) * 96 + cg * 32 + c16 * 8]
                    : (const void*)zerob;
                gl16(&in_s[chunk * 8], src);
            }
        }
        __syncthreads();   // in_s ready

        unsigned int nzb = 0;
        #pragma unroll
        for (int i = 0; i < 4; ++i) {
            int chunk = tid + i * 256;
            if (chunk < 960) {
                uint4 v = *(const uint4*)&in_s[chunk * 8];
                nzb |= v.x | v.y | v.z | v.w;
            }
        }
        bool any = __any(nzb != 0);
        if (lane == 0) s_nz[wid] = any ? 1 : 0;
        __syncthreads();
        if (s_nz[0] | s_nz[1] | s_nz[2] | s_nz[3]) {
            #pragma unroll
            for (int i = 0; i < 6; ++i) {
                int chunk = tid + i * 256;
                int tp = chunk / 768, rem = chunk - tp * 768;
                gl16(&w_s[0][tp * 6144 + rem * 8],
                     &wt2[(((size_t)cg * 26 + tp) * 192) * 32 + rem * 8]);
            }
            __syncthreads();
            for (int pr = 0; pr < 13; ++pr) {
                int cur = pr & 1;
                if (pr < 12) {
                    #pragma unroll
                    for (int i = 0; i < 6; ++i) {
                        int chunk = tid + i * 256;
                        int tp = chunk / 768, rem = chunk - tp * 768;
                        gl16(&w_s[cur ^ 1][tp * 6144 + rem * 8],
                             &wt2[(((size_t)cg * 26 + (pr + 1) * 2 + tp) * 192) * 32 + rem * 8]);
                    }
                }
                #pragma unroll
                for (int t2 = 0; t2 < 2; ++t2) {
                    int tap = pr * 2 + t2;
                    int ki = tap / 5, kj = tap - 5 * ki;
                    if (tap >= 25) { ki = 0; kj = 0; }
                    bf16x8 bfrag[4], afrag[6];
                    #pragma unroll
                    for (int nt = 0; nt < 4; ++nt) {
                        int yy = 2 * nt + coly + ki;
                        int xx = wave_n * 8 + colx + kj;
                        bfrag[nt] = *(const bf16x8*)&in_s[(yy * 20 + xx) * 32 + kg * 8];
                    }
                    #pragma unroll
                    for (int mt = 0; mt < 6; ++mt)
                        afrag[mt] = *(const bf16x8*)
                            &w_s[cur][t2 * 6144 + (wave_m * 96 + mt * 16 + col) * 32 + kg * 8];
                    #pragma unroll
                    for (int mt = 0; mt < 6; ++mt)
                        #pragma unroll
                        for (int nt = 0; nt < 4; ++nt)
                            acc[mt][nt] = __builtin_amdgcn_mfma_f32_16x16x32_bf16(
                                afrag[mt], bfrag[nt], acc[mt][nt], 0, 0, 0);
                }
                __syncthreads();
            }
        }
    }

    float stdv = stdp[0], biasv = biasp[0];
    float inv2s2 = 1.f / (2.f * stdv * stdv);
    float a_own = alphap[coly * 2 + (col & 1)];
    #pragma unroll
    for (int nt = 0; nt < 4; ++nt) {
        int ly = 2 * nt + coly + 2;
        int lx = wave_n * 8 + colx + 2;
        float pnv = 0.f;
        #pragma unroll
        for (int dy = -2; dy <= 2; ++dy)
            #pragma unroll
            for (int dx2 = -2; dx2 <= 2; ++dx2)
                pnv += sq_s[(ly + dy) * 20 + (lx + dx2)];
        int x = x0 + wave_n * 8 + colx;
        int yo = (y0 >> 1) + nt;
        int xo = x >> 1;
        #pragma unroll
        for (int mt = 0; mt < 6; ++mt) {
            int ob = wave_m * 96 + mt * 16 + (kg << 2);
            unsigned short res[4];
            #pragma unroll
            for (int r = 0; r < 4; ++r) {
                float d2 = fmaxf(pnv + wn[ob + r] - 2.f * acc[mt][nt][r], 0.f);
                float g = __expf(-d2 * inv2s2);
                g = (g >= biasv) ? g : 0.f;
                g *= a_own;
                g += __shfl_xor(g, 1);
                g += __shfl_xor(g, 8);
                res[r] = f2bf(0.25f * g);
            }
            if (((col & 1) == 0) && ((col & 8) == 0)) {
                *(ushort4*)&hout[(((size_t)b * 32 + yo) * 32 + xo) * 192 + ob] =
                    make_ushort4(res[0], res[1], res[2], res[3]);
            }
        }
    }
}

// ---------- conv3: MFMA bf16, grid 512, 4 waves x (48o x 64px), 16x8 tile, inline pn3 ----------
__launch_bounds__(256, 2)
__global__ void conv3_mfma(const unsigned short* __restrict__ hin,  // [16][32][32][192] CL
                           const unsigned short* __restrict__ wt3,  // [6][10][192][32]
                           const float* __restrict__ wn,
                           const float* __restrict__ stdp, const float* __restrict__ biasp,
                           const unsigned short* __restrict__ zerob,
                           unsigned short* __restrict__ hout) // [16][384*1024] bf16 CF
{
    __shared__ unsigned short in_s[180 * 32];      // [10][18][32c] 11520 B
    __shared__ unsigned short w_s[2][2 * 96 * 32]; // 24576 B
    __shared__ float pnacc[180];

    int bid = blockIdx.x;
    int sp = bid & 7; bid >>= 3;
    int ot = bid & 3; int b = bid >> 2;
    int x0 = (sp & 1) * 16, y0 = (sp >> 1) * 8, o0 = ot * 96;
    int tid = threadIdx.x;
    int lane = tid & 63, wid = tid >> 6;
    int om = wid >> 1, wn2 = wid & 1;
    int col = lane & 15, kg = lane >> 4;
    int coly = col >> 3, colx = col & 7;

    if (tid < 180) pnacc[tid] = 0.f;

    f32x4 acc[3][4];
    #pragma unroll
    for (int mt = 0; mt < 3; ++mt)
        #pragma unroll
        for (int nt = 0; nt < 4; ++nt) acc[mt][nt] = (f32x4){0.f, 0.f, 0.f, 0.f};

    for (int cg = 0; cg < 6; ++cg) {
        #pragma unroll
        for (int i = 0; i < 3; ++i) {
            int chunk = tid + i * 256;
            if (chunk < 720) {
                int px = chunk >> 2, c16 = chunk & 3;
                int iy = px / 18, ix = px - iy * 18;
                int gy = y0 - 1 + iy, gx = x0 - 1 + ix;
                const void* src = (gy >= 0 && gy < 32 && gx >= 0 && gx < 32)
                    ? (const void*)&hin[(((size_t)b * 32 + gy) * 32 + gx) * 192 + cg * 32 + c16 * 8]
                    : (const void*)zerob;
                gl16(&in_s[chunk * 8], src);
            }
        }
        #pragma unroll
        for (int i = 0; i < 3; ++i) {
            int chunk = tid + i * 256;
            int tp = chunk / 384, rem = chunk - tp * 384;
            gl16(&w_s[0][tp * 3072 + rem * 8],
                 &wt3[(((size_t)cg * 10 + tp) * 192 + o0) * 32 + rem * 8]);
        }
        __syncthreads();

        if (tid < 180) {
            const unsigned short* p = &in_s[tid * 32];
            float a = 0.f;
            #pragma unroll
            for (int c = 0; c < 32; c += 8) {
                bf16x8 v = *(const bf16x8*)&p[c];
                #pragma unroll
                for (int j = 0; j < 8; ++j) { float f = bf2f((unsigned short)v[j]); a += f * f; }
            }
            pnacc[tid] += a;
        }

        for (int pr = 0; pr < 5; ++pr) {
            int cur = pr & 1;
            if (pr < 4) {
                #pragma unroll
                for (int i = 0; i < 3; ++i) {
                    int chunk = tid + i * 256;
                    int tp = chunk / 384, rem = chunk - tp * 384;
                    gl16(&w_s[cur ^ 1][tp * 3072 + rem * 8],
                         &wt3[(((size_t)cg * 10 + (pr + 1) * 2 + tp) * 192 + o0) * 32 + rem * 8]);
                }
            }
            #pragma unroll
            for (int t2 = 0; t2 < 2; ++t2) {
                int tap = pr * 2 + t2;
                int ki = tap / 3, kj = tap - 3 * ki;
                if (tap >= 9) { ki = 0; kj = 0; }
                bf16x8 bfrag[4], afrag[3];
                #pragma unroll
                for (int nt = 0; nt < 4; ++nt) {
                    int yy = 2 * nt + coly + ki;
                    int xx = wn2 * 8 + colx + kj;
                    bfrag[nt] = *(const bf16x8*)&in_s[(yy * 18 + xx) * 32 + kg * 8];
                }
                #pragma unroll
                for (int mt = 0; mt < 3; ++mt)
                    afrag[mt] = *(const bf16x8*)
                        &w_s[cur][(t2 * 96 + om * 48 + mt * 16 + col) * 32 + kg * 8];
                #pragma unroll
                for (int mt = 0; mt < 3; ++mt)
                    #pragma unroll
                    for (int nt = 0; nt < 4; ++nt)
                        acc[mt][nt] = __builtin_amdgcn_mfma_f32_16x16x32_bf16(
                            afrag[mt], bfrag[nt], acc[mt][nt], 0, 0, 0);
            }
            __syncthreads();
        }
    }

    float stdv = stdp[0], biasv = biasp[0];
    float inv2s2 = 1.f / (2.f * stdv * stdv);
    #pragma unroll
    for (int nt = 0; nt < 4; ++nt) {
        int y = y0 + 2 * nt + coly;
        int x = x0 + wn2 * 8 + colx;
        int ly = 2 * nt + coly + 1, lx = wn2 * 8 + colx + 1;
        float pnv = 0.f;
        #pragma unroll
        for (int dy = -1; dy <= 1; ++dy)
            #pragma unroll
            for (int dx = -1; dx <= 1; ++dx)
                pnv += pnacc[(ly + dy) * 18 + (lx + dx)];
        #pragma unroll
        for (int mt = 0; mt < 3; ++mt) {
            int ob = o0 + om * 48 + mt * 16 + (kg << 2);
            #pragma unroll
            for (int r = 0; r < 4; ++r) {
                float d2 = fmaxf(pnv + wn[ob + r] - 2.f * acc[mt][nt][r], 0.f);
                float g = __expf(-d2 * inv2s2);
                g = (g >= biasv) ? g : 0.f;
                hout[((size_t)b * 384 + ob + r) * 1024 + y * 32 + x] = f2bf(g);
            }
        }
    }
}

// ---------- FC: MFMA over K-chunks, zero-chunk skip, atomic accumulate into out ----------
// out pre-initialized to fb by prep_all. All-zero chunks contribute nothing (no atomics).
__launch_bounds__(256, 4)
__global__ void fc_mfma(const unsigned short* __restrict__ h3bf,
                        const float* __restrict__ fw,
                        float* __restrict__ outp)  // [16][100]
{
    __shared__ unsigned short h3s[16 * 520];
    __shared__ unsigned short fws[16 * 520];
    __shared__ float red[4][16][16];
    __shared__ int s_nz[4];
    const size_t KI = 393216;
    int ch = blockIdx.x;
    int i0 = ch * 512;
    int tid = threadIdx.x;
    int lane = tid & 63, wv = tid >> 6;
    int col = lane & 15, kg = lane >> 4;

    unsigned int nzbits = 0;
    #pragma unroll
    for (int it = 0; it < 4; ++it) {
        int c = tid + it * 256;
        int b = c >> 6, off = (c & 63) * 8;
        bf16x8 v = *(const bf16x8*)&h3bf[(size_t)b * KI + i0 + off];
        union { bf16x8 s; unsigned int u[4]; } cv; cv.s = v;
        nzbits |= cv.u[0] | cv.u[1] | cv.u[2] | cv.u[3];
        *(bf16x8*)&h3s[b * 520 + off] = v;
    }
    bool any = __any(nzbits != 0);
    if (lane == 0) s_nz[wv] = any ? 1 : 0;
    __syncthreads();
    if (!(s_nz[0] | s_nz[1] | s_nz[2] | s_nz[3])) return;  // exact: zero contribution

    float4 pre[8];
    #pragma unroll
    for (int it = 0; it < 8; ++it) {
        int c = tid + it * 256;
        int row = c >> 7, off4 = (c & 127) * 4;
        pre[it] = (row < 100) ? *(const float4*)&fw[(size_t)row * KI + i0 + off4]
                              : make_float4(0.f, 0.f, 0.f, 0.f);
    }

    for (int jt = 0; jt < 7; ++jt) {
        int j0 = jt * 16;
        #pragma unroll
        for (int it = 0; it < 8; ++it) {
            int c = tid + it * 256;
            int row = c >> 7, off4 = (c & 127) * 4;
            *(ushort4*)&fws[row * 520 + off4] =
                make_ushort4(f2bf(pre[it].x), f2bf(pre[it].y), f2bf(pre[it].z), f2bf(pre[it].w));
        }
        if (jt < 6) {
            #pragma unroll
            for (int it = 0; it < 8; ++it) {
                int c = tid + it * 256;
                int row = c >> 7, off4 = (c & 127) * 4;
                int j = j0 + 16 + row;
                pre[it] = (j < 100) ? *(const float4*)&fw[(size_t)j * KI + i0 + off4]
                                    : make_float4(0.f, 0.f, 0.f, 0.f);
            }
        }
        __syncthreads();
        f32x4 acc = (f32x4){0.f, 0.f, 0.f, 0.f};
        #pragma unroll
        for (int s = 0; s < 4; ++s) {
            int k = wv * 128 + s * 32 + kg * 8;
            bf16x8 af = *(const bf16x8*)&fws[col * 520 + k];
            bf16x8 bg = *(const bf16x8*)&h3s[col * 520 + k];
            acc = __builtin_amdgcn_mfma_f32_16x16x32_bf16(af, bg, acc, 0, 0, 0);
        }
        #pragma unroll
        for (int r = 0; r < 4; ++r) red[wv][kg * 4 + r][col] = acc[r];
        __syncthreads();
        int j = tid >> 4, bb = tid & 15;
        float s = red[0][j][bb] + red[1][j][bb] + red[2][j][bb] + red[3][j][bb];
        if (j0 + j < 100)
            atomicAdd(&outp[bb * 100 + j0 + j], s);
        __syncthreads();
    }
}

// ---------- launch ----------
extern "C" void kernel_launch(void* const* d_in, const int* in_sizes, int n_in,
                              void* d_out, int out_size, void* d_ws, size_t ws_size,
                              hipStream_t stream) {
    const float* x      = (const float*)d_in[0];
    const float* w1     = (const float*)d_in[1];
    const float* std1   = (const float*)d_in[2];
    const float* bias1  = (const float*)d_in[3];
    const float* alpha1 = (const float*)d_in[4];
    const float* w2     = (const float*)d_in[5];
    const float* std2   = (const float*)d_in[6];
    const float* bias2  = (const float*)d_in[7];
    const float* alpha2 = (const float*)d_in[8];
    const float* w3     = (const float*)d_in[9];
    const float* std3   = (const float*)d_in[10];
    const float* bias3  = (const float*)d_in[11];
    const float* fc_w   = (const float*)d_in[12];
    const float* fc_b   = (const float*)d_in[13];
    float* out = (float*)d_out;
    float* ws  = (float*)d_ws;

    // float region
    float* sbuf  = ws;                  // 65536 (sq1 plane 16*64*64)
    float* wn1   = sbuf + 65536;        // 96
    float* wn2   = wn1 + 96;            // 192
    float* wn3   = wn2 + 192;           // 384
    float* rest  = wn3 + 384 + 32;      // pad -> 16B aligned
    // ushort region
    unsigned short* h1bf = (unsigned short*)rest;  // 6291456
    unsigned short* h2bf = h1bf + 6291456;         // 3145728
    unsigned short* h3bf = h2bf + 3145728;         // 6291456
    unsigned short* xbf  = h3bf + 6291456;         // 1048576
    unsigned short* w1r  = xbf + 1048576;          // 13056
    unsigned short* w2r  = w1r + 13056;            // 479232
    unsigned short* w3r  = w2r + 479232;           // 368640
    unsigned short* zerob = w3r + 368640;          // 64

    dim3 B(TPB);

    prep_all<<<dim3(4562), B, 0, stream>>>(x, w1, w2, w3, fc_b, xbf, w1r, w2r, w3r,
                                           zerob, out, wn1, wn2, wn3);

    conv1_mfma<<<dim3(1024), B, 0, stream>>>(xbf, w1r, wn1, std1, bias1, alpha1,
                                             h1bf, sbuf);

    conv2_mfma<<<dim3(512), B, 0, stream>>>(
        h1bf, w2r, sbuf, wn2, std2, bias2, alpha2, zerob, h2bf);

    conv3_mfma<<<dim3(512), B, 0, stream>>>(
        h2bf, w3r, wn3, std3, bias3, zerob, h3bf);

    fc_mfma<<<dim3(768), B, 0, stream>>>(h3bf, fc_w, out);
}

// Round 18
// 93.144 us; speedup vs baseline: 1.1439x; 1.0125x over previous
//
#include <hip/hip_runtime.h>

#define TPB 256

typedef short bf16x8 __attribute__((ext_vector_type(8)));
typedef float f32x4 __attribute__((ext_vector_type(4)));

__device__ inline unsigned short f2bf(float f) {
    unsigned int u = __float_as_uint(f);
    unsigned int r = (u + 0x7fffu + ((u >> 16) & 1u)) >> 16;
    return (unsigned short)r;
}
__device__ inline float bf2f(unsigned short h) {
    return __uint_as_float(((unsigned int)h) << 16);
}

// async global->LDS 16B copy (dest: linear wave-order, src: per-lane)
__device__ __forceinline__ void gl16(void* lds, const void* g) {
    __builtin_amdgcn_global_load_lds(
        (const __attribute__((address_space(1))) unsigned int*)g,
        (__attribute__((address_space(3))) unsigned int*)lds, 16, 0, 0);
}

// ---------- prep: weight reorders (vectorized), zerob, out=fc_b init, weight norms ----------
// flat region (bid < 472): w1r scalar [0,13056); w2r x8 [13056,72960);
//   w3r x8 [72960,119040); zerob x8 [119040,119048); out-init [119048,120648)
// bid in [472, 640): wn rows (4 per block; 672 rows)
__global__ void prep_all(const float* __restrict__ w1, const float* __restrict__ w2,
                         const float* __restrict__ w3, const float* __restrict__ fb,
                         unsigned short* __restrict__ w1r, unsigned short* __restrict__ w2r,
                         unsigned short* __restrict__ w3r, unsigned short* __restrict__ zerob,
                         float* __restrict__ outp,
                         float* __restrict__ wn1, float* __restrict__ wn2,
                         float* __restrict__ wn3) {
    int bid = blockIdx.x;
    int tid = threadIdx.x;
    if (bid < 472) {
        int i = bid * TPB + tid;
        if (i < 13056) {
            int o = i / 136, d = i - o * 136;
            int tp = d >> 2, c = d & 3;
            float v = 0.f;
            if (tp < 30) {
                int ki = tp / 6, kj = tp - 6 * ki;
                if (kj < 5) v = (c < 3) ? w1[o * 75 + c * 25 + ki * 5 + kj] : -0.5f;
            }
            w1r[i] = f2bf(v);
        } else if (i < 72960) {
            int it = i - 13056;               // vector item: 8 outputs
            int c0 = (it & 3) * 8; int r = it >> 2;
            int o = r % 192; r /= 192;
            int tap = r % 26; int cg = r / 26;
            ushort4 lo, hi;
            unsigned short vv[8];
            #pragma unroll
            for (int j = 0; j < 8; ++j) {
                float v = 0.f;
                if (tap < 25) v = w2[((size_t)o * 96 + cg * 32 + c0 + j) * 25 + tap];
                vv[j] = f2bf(v);
            }
            lo = make_ushort4(vv[0], vv[1], vv[2], vv[3]);
            hi = make_ushort4(vv[4], vv[5], vv[6], vv[7]);
            *(ushort4*)&w2r[(size_t)it * 8] = lo;
            *(ushort4*)&w2r[(size_t)it * 8 + 4] = hi;
        } else if (i < 119040) {
            int it = i - 72960;
            int c0 = (it & 3) * 8; int r = it >> 2;
            int o = r % 192; r /= 192;
            int tap = r % 10; int cg = r / 10;
            unsigned short vv[8];
            #pragma unroll
            for (int j = 0; j < 8; ++j) {
                float v = 0.f;
                if (tap < 9) v = w3[((size_t)o * 192 + cg * 32 + c0 + j) * 9 + tap];
                vv[j] = f2bf(v);
            }
            *(ushort4*)&w3r[(size_t)it * 8]     = make_ushort4(vv[0], vv[1], vv[2], vv[3]);
            *(ushort4*)&w3r[(size_t)it * 8 + 4] = make_ushort4(vv[4], vv[5], vv[6], vv[7]);
        } else if (i < 119048) {
            int it = i - 119040;
            *(ushort4*)&zerob[it * 8]     = make_ushort4(0, 0, 0, 0);
            *(ushort4*)&zerob[it * 8 + 4] = make_ushort4(0, 0, 0, 0);
        } else if (i < 120648) {
            int t = i - 119048;
            outp[t] = fb[t % 100];
        }
    } else {
        int o = (bid - 472) * 4 + (tid >> 6);   // 0..671
        int lane = tid & 63;
        const float* row; float* dst; int D;
        if (o < 96)       { row = w1 + (size_t)o * 75;           D = 75;   dst = wn1 + o; }
        else if (o < 288) { int r = o - 96;  row = w2 + (size_t)r * 2400; D = 2400; dst = wn2 + r; }
        else              { int r = o - 288; row = w3 + (size_t)r * 1728; D = 1728; dst = wn3 + r; }
        float acc = 0.f;
        for (int i = lane; i < D; i += 64) { float v = row[i]; acc += v * v; }
        #pragma unroll
        for (int off = 32; off >= 1; off >>= 1) acc += __shfl_down(acc, off);
        if (lane == 0) *dst = acc;
    }
}

// ---------- conv1: MFMA bf16, stages x directly (bf16 + sq ch), pn folded via sq channel ----------
__launch_bounds__(256, 2)
__global__ void conv1_mfma(const float* __restrict__ x,
                           const unsigned short* __restrict__ w1r,
                           const float* __restrict__ wn,
                           const float* __restrict__ stdp, const float* __restrict__ biasp,
                           const float* __restrict__ alphap,
                           unsigned short* __restrict__ out,  // [16][64][64][96] bf16 CL
                           float* __restrict__ sqout)         // [16][64][64] fp32
{
    __shared__ unsigned short in_s[22 * 20 * 4];
    __shared__ unsigned short w_s[96 * 136];

    int bid = blockIdx.x;
    int tx = bid & 7; bid >>= 3;
    int ty = bid & 7; bid >>= 3;
    int b = bid;
    int x0 = tx * 16, y0 = ty * 16;
    int tid = threadIdx.x;
    int lane = tid & 63, wv = tid >> 6;
    int col = lane & 15, kg = lane >> 4;

    for (int idx = tid; idx < 21 * 20; idx += 256) {
        int py = idx / 20, px = idx - py * 20;
        int gy = y0 - 2 + py, gx = x0 - 2 + px;
        ushort4 v = make_ushort4(0, 0, 0, 0);
        if (gy >= 0 && gy < 128 && gx >= 0 && gx < 128) {
            const float* xb = x + (size_t)b * 49152 + gy * 128 + gx;
            float v0 = xb[0], v1 = xb[16384], v2 = xb[32768];
            v = make_ushort4(f2bf(v0), f2bf(v1), f2bf(v2),
                             f2bf(v0 * v0 + v1 * v1 + v2 * v2));
        }
        *(ushort4*)&in_s[idx * 4] = v;
    }
    for (int idx = tid; idx < 1632; idx += 256)
        *(bf16x8*)&w_s[idx * 8] = *(const bf16x8*)&w1r[idx * 8];
    __syncthreads();

    f32x4 acc[6][4];
    #pragma unroll
    for (int mt = 0; mt < 6; ++mt)
        #pragma unroll
        for (int n = 0; n < 4; ++n) acc[mt][n] = (f32x4){0.f, 0.f, 0.f, 0.f};

    #pragma unroll
    for (int ks = 0; ks < 4; ++ks) {
        int tap0 = ks * 8 + kg * 2;
        int ki = tap0 / 6, kj = tap0 - 6 * ki;
        bf16x8 bfrag[4];
        #pragma unroll
        for (int n = 0; n < 4; ++n) {
            int row = wv * 4 + n + ki;
            int ix = col + kj;
            const unsigned short* p = &in_s[(row * 20 + ix) * 4];
            union { bf16x8 v; uint2 u[2]; } tmp;
            tmp.u[0] = *(const uint2*)p;
            tmp.u[1] = *(const uint2*)(p + 4);
            bfrag[n] = tmp.v;
        }
        bf16x8 afrag[6];
        #pragma unroll
        for (int mt = 0; mt < 6; ++mt)
            afrag[mt] = *(const bf16x8*)&w_s[(mt * 16 + col) * 136 + ks * 32 + kg * 8];
        #pragma unroll
        for (int mt = 0; mt < 6; ++mt)
            #pragma unroll
            for (int n = 0; n < 4; ++n)
                acc[mt][n] = __builtin_amdgcn_mfma_f32_16x16x32_bf16(
                    afrag[mt], bfrag[n], acc[mt][n], 0, 0, 0);
    }

    float stdv = stdp[0], biasv = biasp[0];
    float inv2s2 = 1.f / (2.f * stdv * stdv);
    float a00 = alphap[0], a01 = alphap[1], a10 = alphap[2], a11 = alphap[3];
    int dx = col & 1;
    float ax0 = dx ? a01 : a00;
    float ax1 = dx ? a11 : a10;

    float sqa[2] = {0.f, 0.f};
    #pragma unroll
    for (int mt = 0; mt < 6; ++mt) {
        #pragma unroll
        for (int p2 = 0; p2 < 2; ++p2) {
            unsigned short res[4];
            #pragma unroll
            for (int r = 0; r < 4; ++r) {
                int o = mt * 16 + kg * 4 + r;
                float wno = wn[o];
                float d20 = fmaxf(wno - 2.f * acc[mt][2 * p2][r], 0.f);
                float d21 = fmaxf(wno - 2.f * acc[mt][2 * p2 + 1][r], 0.f);
                float g0 = __expf(-d20 * inv2s2);
                float g1 = __expf(-d21 * inv2s2);
                g0 = (g0 >= biasv) ? g0 : 0.f;
                g1 = (g1 >= biasv) ? g1 : 0.f;
                float s = ax0 * g0 + ax1 * g1;
                s += __shfl_xor(s, 1);
                res[r] = f2bf(0.25f * s);
                float vv = bf2f(res[r]);
                sqa[p2] += vv * vv;
            }
            if (dx == 0) {
                int yo = ty * 8 + wv * 2 + p2, xo = tx * 8 + (col >> 1);
                *(ushort4*)&out[(((size_t)b * 64 + yo) * 64 + xo) * 96 + mt * 16 + kg * 4] =
                    make_ushort4(res[0], res[1], res[2], res[3]);
            }
        }
    }
    #pragma unroll
    for (int p2 = 0; p2 < 2; ++p2) {
        float s = sqa[p2];
        s += __shfl_xor(s, 16);
        s += __shfl_xor(s, 32);
        if (dx == 0 && kg == 0) {
            int yo = ty * 8 + wv * 2 + p2, xo = tx * 8 + (col >> 1);
            sqout[((size_t)b * 64 + yo) * 64 + xo] = s;
        }
    }
}

// ---------- conv2: 192o x 128px per block, 4 waves (2m x 2n), zero-skip before weights ----------
__launch_bounds__(256, 2)
__global__ void conv2_mfma(const unsigned short* __restrict__ hin,
                           const unsigned short* __restrict__ wt2,  // [3][26][192][32]
                           const float* __restrict__ sq1,           // [16][64][64] fp32
                           const float* __restrict__ wn,
                           const float* __restrict__ stdp, const float* __restrict__ biasp,
                           const float* __restrict__ alphap,
                           const unsigned short* __restrict__ zerob,
                           unsigned short* __restrict__ hout) // [16][32][32][192] CL bf16
{
    __shared__ unsigned short in_s[240 * 32];       // 15360 B
    __shared__ unsigned short w_s[2][2 * 192 * 32]; // 49152 B
    __shared__ float sq_s[240];
    __shared__ int s_nz[4];

    int bid = blockIdx.x;
    int xt = bid & 3; bid >>= 2;
    int yt = bid & 7; bid >>= 3;
    int b = bid;
    int x0 = xt * 16, y0 = yt * 8;
    int tid = threadIdx.x;
    int lane = tid & 63, wid = tid >> 6;
    int wave_m = wid >> 1, wave_n = wid & 1;
    int col = lane & 15, kg = lane >> 4;
    int coly = col >> 3, colx = col & 7;

    if (tid < 240) {
        int r = tid / 20, c = tid - r * 20;
        int gy = y0 - 2 + r, gx = x0 - 2 + c;
        float v = 0.f;
        if (gy >= 0 && gy < 64 && gx >= 0 && gx < 64)
            v = sq1[((size_t)b * 64 + gy) * 64 + gx];
        sq_s[tid] = v;
    }

    f32x4 acc[6][4];
    #pragma unroll
    for (int mt = 0; mt < 6; ++mt)
        #pragma unroll
        for (int nt = 0; nt < 4; ++nt) acc[mt][nt] = (f32x4){0.f, 0.f, 0.f, 0.f};

    for (int cg = 0; cg < 3; ++cg) {
        #pragma unroll
        for (int i = 0; i < 4; ++i) {
            int chunk = tid + i * 256;
            if (chunk < 960) {
                int px = chunk >> 2, c16 = chunk & 3;
                int iy = px / 20, ix = px - iy * 20;
                int gy = y0 - 2 + iy, gx = x0 - 2 + ix;
                const void* src = (gy >= 0 && gy < 64 && gx >= 0 && gx < 64)
                    ? (const void*)&hin[(((size_t)b * 64 + gy) * 64 + gx) * 96 + cg * 32 + c16 * 8]
                    : (const void*)zerob;
                gl16(&in_s[chunk * 8], src);
            }
        }
        __syncthreads();   // in_s ready

        unsigned int nzb = 0;
        #pragma unroll
        for (int i = 0; i < 4; ++i) {
            int chunk = tid + i * 256;
            if (chunk < 960) {
                uint4 v = *(const uint4*)&in_s[chunk * 8];
                nzb |= v.x | v.y | v.z | v.w;
            }
        }
        bool any = __any(nzb != 0);
        if (lane == 0) s_nz[wid] = any ? 1 : 0;
        __syncthreads();
        if (s_nz[0] | s_nz[1] | s_nz[2] | s_nz[3]) {
            #pragma unroll
            for (int i = 0; i < 6; ++i) {
                int chunk = tid + i * 256;
                int tp = chunk / 768, rem = chunk - tp * 768;
                gl16(&w_s[0][tp * 6144 + rem * 8],
                     &wt2[(((size_t)cg * 26 + tp) * 192) * 32 + rem * 8]);
            }
            __syncthreads();
            for (int pr = 0; pr < 13; ++pr) {
                int cur = pr & 1;
                if (pr < 12) {
                    #pragma unroll
                    for (int i = 0; i < 6; ++i) {
                        int chunk = tid + i * 256;
                        int tp = chunk / 768, rem = chunk - tp * 768;
                        gl16(&w_s[cur ^ 1][tp * 6144 + rem * 8],
                             &wt2[(((size_t)cg * 26 + (pr + 1) * 2 + tp) * 192) * 32 + rem * 8]);
                    }
                }
                #pragma unroll
                for (int t2 = 0; t2 < 2; ++t2) {
                    int tap = pr * 2 + t2;
                    int ki = tap / 5, kj = tap - 5 * ki;
                    if (tap >= 25) { ki = 0; kj = 0; }
                    bf16x8 bfrag[4], afrag[6];
                    #pragma unroll
                    for (int nt = 0; nt < 4; ++nt) {
                        int yy = 2 * nt + coly + ki;
                        int xx = wave_n * 8 + colx + kj;
                        bfrag[nt] = *(const bf16x8*)&in_s[(yy * 20 + xx) * 32 + kg * 8];
                    }
                    #pragma unroll
                    for (int mt = 0; mt < 6; ++mt)
                        afrag[mt] = *(const bf16x8*)
                            &w_s[cur][t2 * 6144 + (wave_m * 96 + mt * 16 + col) * 32 + kg * 8];
                    #pragma unroll
                    for (int mt = 0; mt < 6; ++mt)
                        #pragma unroll
                        for (int nt = 0; nt < 4; ++nt)
                            acc[mt][nt] = __builtin_amdgcn_mfma_f32_16x16x32_bf16(
                                afrag[mt], bfrag[nt], acc[mt][nt], 0, 0, 0);
                }
                __syncthreads();
            }
        }
    }

    float stdv = stdp[0], biasv = biasp[0];
    float inv2s2 = 1.f / (2.f * stdv * stdv);
    float a_own = alphap[coly * 2 + (col & 1)];
    #pragma unroll
    for (int nt = 0; nt < 4; ++nt) {
        int ly = 2 * nt + coly + 2;
        int lx = wave_n * 8 + colx + 2;
        float pnv = 0.f;
        #pragma unroll
        for (int dy = -2; dy <= 2; ++dy)
            #pragma unroll
            for (int dx2 = -2; dx2 <= 2; ++dx2)
                pnv += sq_s[(ly + dy) * 20 + (lx + dx2)];
        int x = x0 + wave_n * 8 + colx;
        int yo = (y0 >> 1) + nt;
        int xo = x >> 1;
        #pragma unroll
        for (int mt = 0; mt < 6; ++mt) {
            int ob = wave_m * 96 + mt * 16 + (kg << 2);
            unsigned short res[4];
            #pragma unroll
            for (int r = 0; r < 4; ++r) {
                float d2 = fmaxf(pnv + wn[ob + r] - 2.f * acc[mt][nt][r], 0.f);
                float g = __expf(-d2 * inv2s2);
                g = (g >= biasv) ? g : 0.f;
                g *= a_own;
                g += __shfl_xor(g, 1);
                g += __shfl_xor(g, 8);
                res[r] = f2bf(0.25f * g);
            }
            if (((col & 1) == 0) && ((col & 8) == 0)) {
                *(ushort4*)&hout[(((size_t)b * 32 + yo) * 32 + xo) * 192 + ob] =
                    make_ushort4(res[0], res[1], res[2], res[3]);
            }
        }
    }
}

// ---------- conv3: MFMA bf16, grid 512, 4 waves x (48o x 64px), 16x8 tile, inline pn3 ----------
__launch_bounds__(256, 2)
__global__ void conv3_mfma(const unsigned short* __restrict__ hin,  // [16][32][32][192] CL
                           const unsigned short* __restrict__ wt3,  // [6][10][192][32]
                           const float* __restrict__ wn,
                           const float* __restrict__ stdp, const float* __restrict__ biasp,
                           const unsigned short* __restrict__ zerob,
                           unsigned short* __restrict__ hout) // [16][384*1024] bf16 CF
{
    __shared__ unsigned short in_s[180 * 32];      // [10][18][32c] 11520 B
    __shared__ unsigned short w_s[2][2 * 96 * 32]; // 24576 B
    __shared__ float pnacc[180];

    int bid = blockIdx.x;
    int sp = bid & 7; bid >>= 3;
    int ot = bid & 3; int b = bid >> 2;
    int x0 = (sp & 1) * 16, y0 = (sp >> 1) * 8, o0 = ot * 96;
    int tid = threadIdx.x;
    int lane = tid & 63, wid = tid >> 6;
    int om = wid >> 1, wn2 = wid & 1;
    int col = lane & 15, kg = lane >> 4;
    int coly = col >> 3, colx = col & 7;

    if (tid < 180) pnacc[tid] = 0.f;

    f32x4 acc[3][4];
    #pragma unroll
    for (int mt = 0; mt < 3; ++mt)
        #pragma unroll
        for (int nt = 0; nt < 4; ++nt) acc[mt][nt] = (f32x4){0.f, 0.f, 0.f, 0.f};

    for (int cg = 0; cg < 6; ++cg) {
        #pragma unroll
        for (int i = 0; i < 3; ++i) {
            int chunk = tid + i * 256;
            if (chunk < 720) {
                int px = chunk >> 2, c16 = chunk & 3;
                int iy = px / 18, ix = px - iy * 18;
                int gy = y0 - 1 + iy, gx = x0 - 1 + ix;
                const void* src = (gy >= 0 && gy < 32 && gx >= 0 && gx < 32)
                    ? (const void*)&hin[(((size_t)b * 32 + gy) * 32 + gx) * 192 + cg * 32 + c16 * 8]
                    : (const void*)zerob;
                gl16(&in_s[chunk * 8], src);
            }
        }
        #pragma unroll
        for (int i = 0; i < 3; ++i) {
            int chunk = tid + i * 256;
            int tp = chunk / 384, rem = chunk - tp * 384;
            gl16(&w_s[0][tp * 3072 + rem * 8],
                 &wt3[(((size_t)cg * 10 + tp) * 192 + o0) * 32 + rem * 8]);
        }
        __syncthreads();

        if (tid < 180) {
            const unsigned short* p = &in_s[tid * 32];
            float a = 0.f;
            #pragma unroll
            for (int c = 0; c < 32; c += 8) {
                bf16x8 v = *(const bf16x8*)&p[c];
                #pragma unroll
                for (int j = 0; j < 8; ++j) { float f = bf2f((unsigned short)v[j]); a += f * f; }
            }
            pnacc[tid] += a;
        }

        for (int pr = 0; pr < 5; ++pr) {
            int cur = pr & 1;
            if (pr < 4) {
                #pragma unroll
                for (int i = 0; i < 3; ++i) {
                    int chunk = tid + i * 256;
                    int tp = chunk / 384, rem = chunk - tp * 384;
                    gl16(&w_s[cur ^ 1][tp * 3072 + rem * 8],
                         &wt3[(((size_t)cg * 10 + (pr + 1) * 2 + tp) * 192 + o0) * 32 + rem * 8]);
                }
            }
            #pragma unroll
            for (int t2 = 0; t2 < 2; ++t2) {
                int tap = pr * 2 + t2;
                int ki = tap / 3, kj = tap - 3 * ki;
                if (tap >= 9) { ki = 0; kj = 0; }
                bf16x8 bfrag[4], afrag[3];
                #pragma unroll
                for (int nt = 0; nt < 4; ++nt) {
                    int yy = 2 * nt + coly + ki;
                    int xx = wn2 * 8 + colx + kj;
                    bfrag[nt] = *(const bf16x8*)&in_s[(yy * 18 + xx) * 32 + kg * 8];
                }
                #pragma unroll
                for (int mt = 0; mt < 3; ++mt)
                    afrag[mt] = *(const bf16x8*)
                        &w_s[cur][(t2 * 96 + om * 48 + mt * 16 + col) * 32 + kg * 8];
                #pragma unroll
                for (int mt = 0; mt < 3; ++mt)
                    #pragma unroll
                    for (int nt = 0; nt < 4; ++nt)
                        acc[mt][nt] = __builtin_amdgcn_mfma_f32_16x16x32_bf16(
                            afrag[mt], bfrag[nt], acc[mt][nt], 0, 0, 0);
            }
            __syncthreads();
        }
    }

    float stdv = stdp[0], biasv = biasp[0];
    float inv2s2 = 1.f / (2.f * stdv * stdv);
    #pragma unroll
    for (int nt = 0; nt < 4; ++nt) {
        int y = y0 + 2 * nt + coly;
        int x = x0 + wn2 * 8 + colx;
        int ly = 2 * nt + coly + 1, lx = wn2 * 8 + colx + 1;
        float pnv = 0.f;
        #pragma unroll
        for (int dy = -1; dy <= 1; ++dy)
            #pragma unroll
            for (int dx = -1; dx <= 1; ++dx)
                pnv += pnacc[(ly + dy) * 18 + (lx + dx)];
        #pragma unroll
        for (int mt = 0; mt < 3; ++mt) {
            int ob = o0 + om * 48 + mt * 16 + (kg << 2);
            #pragma unroll
            for (int r = 0; r < 4; ++r) {
                float d2 = fmaxf(pnv + wn[ob + r] - 2.f * acc[mt][nt][r], 0.f);
                float g = __expf(-d2 * inv2s2);
                g = (g >= biasv) ? g : 0.f;
                hout[((size_t)b * 384 + ob + r) * 1024 + y * 32 + x] = f2bf(g);
            }
        }
    }
}

// ---------- FC: MFMA over K-chunks, zero-chunk skip, atomic accumulate into out ----------
// out pre-initialized to fb by prep_all. All-zero chunks contribute nothing (no atomics).
__launch_bounds__(256, 4)
__global__ void fc_mfma(const unsigned short* __restrict__ h3bf,
                        const float* __restrict__ fw,
                        float* __restrict__ outp)  // [16][100]
{
    __shared__ unsigned short h3s[16 * 520];
    __shared__ unsigned short fws[16 * 520];
    __shared__ float red[4][16][16];
    __shared__ int s_nz[4];
    const size_t KI = 393216;
    int ch = blockIdx.x;
    int i0 = ch * 512;
    int tid = threadIdx.x;
    int lane = tid & 63, wv = tid >> 6;
    int col = lane & 15, kg = lane >> 4;

    unsigned int nzbits = 0;
    #pragma unroll
    for (int it = 0; it < 4; ++it) {
        int c = tid + it * 256;
        int b = c >> 6, off = (c & 63) * 8;
        bf16x8 v = *(const bf16x8*)&h3bf[(size_t)b * KI + i0 + off];
        union { bf16x8 s; unsigned int u[4]; } cv; cv.s = v;
        nzbits |= cv.u[0] | cv.u[1] | cv.u[2] | cv.u[3];
        *(bf16x8*)&h3s[b * 520 + off] = v;
    }
    bool any = __any(nzbits != 0);
    if (lane == 0) s_nz[wv] = any ? 1 : 0;
    __syncthreads();
    if (!(s_nz[0] | s_nz[1] | s_nz[2] | s_nz[3])) return;  // exact: zero contribution

    float4 pre[8];
    #pragma unroll
    for (int it = 0; it < 8; ++it) {
        int c = tid + it * 256;
        int row = c >> 7, off4 = (c & 127) * 4;
        pre[it] = (row < 100) ? *(const float4*)&fw[(size_t)row * KI + i0 + off4]
                              : make_float4(0.f, 0.f, 0.f, 0.f);
    }

    for (int jt = 0; jt < 7; ++jt) {
        int j0 = jt * 16;
        #pragma unroll
        for (int it = 0; it < 8; ++it) {
            int c = tid + it * 256;
            int row = c >> 7, off4 = (c & 127) * 4;
            *(ushort4*)&fws[row * 520 + off4] =
                make_ushort4(f2bf(pre[it].x), f2bf(pre[it].y), f2bf(pre[it].z), f2bf(pre[it].w));
        }
        if (jt < 6) {
            #pragma unroll
            for (int it = 0; it < 8; ++it) {
                int c = tid + it * 256;
                int row = c >> 7, off4 = (c & 127) * 4;
                int j = j0 + 16 + row;
                pre[it] = (j < 100) ? *(const float4*)&fw[(size_t)j * KI + i0 + off4]
                                    : make_float4(0.f, 0.f, 0.f, 0.f);
            }
        }
        __syncthreads();
        f32x4 acc = (f32x4){0.f, 0.f, 0.f, 0.f};
        #pragma unroll
        for (int s = 0; s < 4; ++s) {
            int k = wv * 128 + s * 32 + kg * 8;
            bf16x8 af = *(const bf16x8*)&fws[col * 520 + k];
            bf16x8 bg = *(const bf16x8*)&h3s[col * 520 + k];
            acc = __builtin_amdgcn_mfma_f32_16x16x32_bf16(af, bg, acc, 0, 0, 0);
        }
        #pragma unroll
        for (int r = 0; r < 4; ++r) red[wv][kg * 4 + r][col] = acc[r];
        __syncthreads();
        int j = tid >> 4, bb = tid & 15;
        float s = red[0][j][bb] + red[1][j][bb] + red[2][j][bb] + red[3][j][bb];
        if (j0 + j < 100)
            atomicAdd(&outp[bb * 100 + j0 + j], s);
        __syncthreads();
    }
}

// ---------- launch ----------
extern "C" void kernel_launch(void* const* d_in, const int* in_sizes, int n_in,
                              void* d_out, int out_size, void* d_ws, size_t ws_size,
                              hipStream_t stream) {
    const float* x      = (const float*)d_in[0];
    const float* w1     = (const float*)d_in[1];
    const float* std1   = (const float*)d_in[2];
    const float* bias1  = (const float*)d_in[3];
    const float* alpha1 = (const float*)d_in[4];
    const float* w2     = (const float*)d_in[5];
    const float* std2   = (const float*)d_in[6];
    const float* bias2  = (const float*)d_in[7];
    const float* alpha2 = (const float*)d_in[8];
    const float* w3     = (const float*)d_in[9];
    const float* std3   = (const float*)d_in[10];
    const float* bias3  = (const float*)d_in[11];
    const float* fc_w   = (const float*)d_in[12];
    const float* fc_b   = (const float*)d_in[13];
    float* out = (float*)d_out;
    float* ws  = (float*)d_ws;

    // float region
    float* sbuf  = ws;                  // 65536 (sq1 plane 16*64*64)
    float* wn1   = sbuf + 65536;        // 96
    float* wn2   = wn1 + 96;            // 192
    float* wn3   = wn2 + 192;           // 384
    float* rest  = wn3 + 384 + 32;      // pad -> 16B aligned
    // ushort region
    unsigned short* h1bf = (unsigned short*)rest;  // 6291456
    unsigned short* h2bf = h1bf + 6291456;         // 3145728
    unsigned short* h3bf = h2bf + 3145728;         // 6291456
    unsigned short* w1r  = h3bf + 6291456;         // 13056
    unsigned short* w2r  = w1r + 13056;            // 479232
    unsigned short* w3r  = w2r + 479232;           // 368640
    unsigned short* zerob = w3r + 368640;          // 64

    dim3 B(TPB);

    prep_all<<<dim3(640), B, 0, stream>>>(w1, w2, w3, fc_b, w1r, w2r, w3r,
                                          zerob, out, wn1, wn2, wn3);

    conv1_mfma<<<dim3(1024), B, 0, stream>>>(x, w1r, wn1, std1, bias1, alpha1,
                                             h1bf, sbuf);

    conv2_mfma<<<dim3(512), B, 0, stream>>>(
        h1bf, w2r, sbuf, wn2, std2, bias2, alpha2, zerob, h2bf);

    conv3_mfma<<<dim3(512), B, 0, stream>>>(
        h2bf, w3r, wn3, std3, bias3, zerob, h3bf);

    fc_mfma<<<dim3(768), B, 0, stream>>>(h3bf, fc_w, out);
}